// Round 9
// baseline (330.690 us; speedup 1.0000x reference)
//
#include <hip/hip_runtime.h>
#include <hip/hip_bf16.h>

typedef unsigned short u16;
typedef unsigned int u32;

#define T_TOK 16384
#define DIM   1024
#define NEXP  8

// ---------- workspace layout (bytes) ----------
#define XB_OFF      0
#define WB_OFF      33554432
#define CNT_OFF     50331648
#define LIST_OFF    50332160
#define SELW_OFF    50856448
#define CONTRIB_OFF 51380736
#define WS_NEED     118489600ULL

__device__ __forceinline__ u16 f2bf(float f) {
    u32 u = __float_as_uint(f);
    u += 0x7fff + ((u >> 16) & 1);   // round-to-nearest-even
    return (u16)(u >> 16);
}
__device__ __forceinline__ float bf2f(u16 u) {
    return __uint_as_float(((u32)u) << 16);
}

// Router + fused expert-weight cvt (unchanged from r8).
#define RT_PB 32

__global__ __launch_bounds__(256) void k_router(
    const float* __restrict__ x, const float* __restrict__ gw,
    const float* __restrict__ gb, float* __restrict__ logits,
    u16* __restrict__ xb, int* __restrict__ counts,
    int* __restrict__ lists, float4* __restrict__ selw,
    const float* __restrict__ ew, u16* __restrict__ wb)
{
    const int tid  = threadIdx.x;
    const int lane = tid & 63;
    const int w    = tid >> 6;

    __shared__ int   s_sel0[RT_PB], s_sel1[RT_PB];
    __shared__ int   s_lcnt[NEXP], s_gbase[NEXP];

    if (tid < NEXP) s_lcnt[tid] = 0;

    for (int i = 0; i < 8; ++i) {
        const int l = w * 8 + i;
        const int t = blockIdx.x * RT_PB + l;

        const float* xr = x + (size_t)t * DIM;
        float4 xs[4];
#pragma unroll
        for (int j = 0; j < 4; ++j)
            xs[j] = *reinterpret_cast<const float4*>(xr + (j * 64 + lane) * 4);

        float acc[NEXP];
#pragma unroll
        for (int e = 0; e < NEXP; ++e) {
            const float* gr = gw + e * DIM;
            float s = 0.f;
#pragma unroll
            for (int j = 0; j < 4; ++j) {
                float4 g = *reinterpret_cast<const float4*>(gr + (j * 64 + lane) * 4);
                s += xs[j].x * g.x + xs[j].y * g.y + xs[j].z * g.z + xs[j].w * g.w;
            }
            acc[e] = s;
        }
#pragma unroll
        for (int off = 1; off < 64; off <<= 1) {
#pragma unroll
            for (int e = 0; e < NEXP; ++e) acc[e] += __shfl_xor(acc[e], off);
        }
#pragma unroll
        for (int e = 0; e < NEXP; ++e) acc[e] += gb[e];

        int i0 = 0; float v0 = acc[0];
#pragma unroll
        for (int e = 1; e < NEXP; ++e) if (acc[e] > v0) { v0 = acc[e]; i0 = e; }
        int i1 = -1; float v1 = -3.4e38f;
#pragma unroll
        for (int e = 0; e < NEXP; ++e) if (e != i0 && acc[e] > v1) { v1 = acc[e]; i1 = e; }
        float e1  = __expf(v1 - v0);
        float inv = 1.f / (1.f + e1);
        float w0 = inv, w1 = e1 * inv;

        u16* xrow = xb + (size_t)t * DIM;
#pragma unroll
        for (int j = 0; j < 4; ++j) {
            int c = (j * 64 + lane) * 4;
            float4 v = xs[j];
            ushort4 u;
            u.x = f2bf(v.x); u.y = f2bf(v.y); u.z = f2bf(v.z); u.w = f2bf(v.w);
            *reinterpret_cast<ushort4*>(xrow + c) = u;
        }
        if (lane == 0) {
            float4 lo = make_float4(acc[0], acc[1], acc[2], acc[3]);
            float4 hi = make_float4(acc[4], acc[5], acc[6], acc[7]);
            *reinterpret_cast<float4*>(logits + (size_t)t * NEXP)     = lo;
            *reinterpret_cast<float4*>(logits + (size_t)t * NEXP + 4) = hi;
            selw[t] = make_float4(__int_as_float(i0), __int_as_float(i1), w0, w1);
            s_sel0[l] = i0; s_sel1[l] = i1;
        }
    }
    __syncthreads();

    int i0 = 0, i1 = 0, r0 = 0, r1 = 0;
    if (tid < RT_PB) {
        i0 = s_sel0[tid]; i1 = s_sel1[tid];
        r0 = atomicAdd(&s_lcnt[i0], 1);
        r1 = atomicAdd(&s_lcnt[i1], 1);
    }
    __syncthreads();
    if (tid < NEXP)
        s_gbase[tid] = atomicAdd(&counts[tid * 16], s_lcnt[tid]);
    __syncthreads();
    if (tid < RT_PB) {
        int t  = blockIdx.x * RT_PB + tid;
        lists[i0 * T_TOK + s_gbase[i0] + r0] = t * 2;
        lists[i1 * T_TOK + s_gbase[i1] + r1] = t * 2 + 1;
    }

    const int n4 = NEXP * DIM * DIM / 4;
    const int stride = gridDim.x * 256;
    for (int i = blockIdx.x * 256 + tid; i < n4; i += stride) {
        float4 v = reinterpret_cast<const float4*>(ew)[i];
        ushort4 u;
        u.x = f2bf(v.x); u.y = f2bf(v.y); u.z = f2bf(v.z); u.w = f2bf(v.w);
        reinterpret_cast<ushort4*>(wb)[i] = u;
    }
}

// ======================= grouped GEMM, r8 structure, ABLATION TEMPLATE.
// MODE 0 = full (correct output, launched LAST)
// MODE 1 = compute-core only: ds_read+MFMA+BAR, no staging/vmcnt (probe)
// MODE 2 = staging machinery only: STAGE+VMW+BAR, no ds_read/MFMA (probe)
// Probes run BEFORE mode 0 and their contrib writes are overwritten -> the
// validated output is unaffected. rocprof reports each dispatch's duration:
// this decomposes the invariant 104us/28% across r5-r8 into its two halves.

typedef __attribute__((ext_vector_type(8))) short bf16x8;
typedef __attribute__((ext_vector_type(4))) float f32x4;

#define GLDS16(g, l) __builtin_amdgcn_global_load_lds( \
    (const __attribute__((address_space(1))) void*)(g), \
    (__attribute__((address_space(3))) void*)(l), 16, 0, 0)

#define BAR() __builtin_amdgcn_s_barrier()
#define PRIO1() __builtin_amdgcn_s_setprio(1)
#define PRIO0() __builtin_amdgcn_s_setprio(0)
#define VMW4() asm volatile("s_waitcnt vmcnt(4)" ::: "memory")
#define VMW0() asm volatile("s_waitcnt vmcnt(0)" ::: "memory")

template<int MODE>
__global__ __launch_bounds__(512, 2) void k_gemm(
    const u16* __restrict__ xb, const u16* __restrict__ wb,
    const int* __restrict__ counts, const int* __restrict__ lists,
    const float4* __restrict__ selw, u16* __restrict__ contrib,
    float* __restrict__ out)
{
    __shared__ u16 lds[49152];   // 96 KiB: buf b*16384 | A [0,8192) | B [8192,16384)

    const int bid = (blockIdx.x & 7) * 256 + (blockIdx.x >> 3);
    const int e   = bid >> 8;
    const int mt  = (bid >> 2) & 63;
    const int nt  = bid & 3;
    const int cnt = counts[e * 16];
    if (mt * 256 >= cnt) return;

    const int tid  = threadIdx.x;
    const int lane = tid & 63;
    const int wid  = tid >> 6;
    const int wm   = wid >> 2;   // 0..1
    const int wn   = wid & 3;    // 0..3
    const int listbase = e * T_TOK;

    const int srow = tid >> 2;
    const int cA   = (((tid & 3) - (tid >> 3)) & 3) * 8;
    int tokA[2];
#pragma unroll
    for (int l = 0; l < 2; ++l) {
        int slot = mt * 256 + l * 128 + srow;
        tokA[l] = lists[listbase + (slot < cnt ? slot : cnt - 1)] >> 1;
    }
    const u16* srcA0 = xb + (size_t)tokA[0] * DIM + cA;
    const u16* srcA1 = xb + (size_t)tokA[1] * DIM + cA;
    const u16* srcB0 = wb + ((size_t)e << 20) + (size_t)(nt * 256 + srow) * DIM + cA;
    const u16* srcB1 = srcB0 + (size_t)128 * DIM;

#define STAGE(b, kk) do { \
    GLDS16(srcA0 + (kk), &lds[(b) * 16384 + wid * 512]); \
    GLDS16(srcA1 + (kk), &lds[(b) * 16384 + 4096 + wid * 512]); \
    GLDS16(srcB0 + (kk), &lds[(b) * 16384 + 8192 + wid * 512]); \
    GLDS16(srcB1 + (kk), &lds[(b) * 16384 + 12288 + wid * 512]); } while (0)

    const int cs8  = (((lane >> 4) + ((lane >> 1) & 3)) & 3) * 8;
    const int offA = wm * 4096 + (lane & 15) * 32 + cs8;
    const int offB = 8192 + wn * 2048 + (lane & 15) * 32 + cs8;

    bf16x8 Af[4], Bf[4];
    f32x4 acc[8][4];
#pragma unroll
    for (int mi = 0; mi < 8; ++mi)
#pragma unroll
        for (int ni = 0; ni < 4; ++ni) acc[mi][ni] = (f32x4)0.f;

#define LDA4(b, q) do { \
    Af[0] = *(const bf16x8*)&lds[(b) * 16384 + ((q) * 4 + 0) * 512 + offA]; \
    Af[1] = *(const bf16x8*)&lds[(b) * 16384 + ((q) * 4 + 1) * 512 + offA]; \
    Af[2] = *(const bf16x8*)&lds[(b) * 16384 + ((q) * 4 + 2) * 512 + offA]; \
    Af[3] = *(const bf16x8*)&lds[(b) * 16384 + ((q) * 4 + 3) * 512 + offA]; } while (0)
#define LDB4(b) do { \
    Bf[0] = *(const bf16x8*)&lds[(b) * 16384 + 0 * 512 + offB]; \
    Bf[1] = *(const bf16x8*)&lds[(b) * 16384 + 1 * 512 + offB]; \
    Bf[2] = *(const bf16x8*)&lds[(b) * 16384 + 2 * 512 + offB]; \
    Bf[3] = *(const bf16x8*)&lds[(b) * 16384 + 3 * 512 + offB]; } while (0)
#define MFMA16(q) do { \
    _Pragma("unroll") \
    for (int i = 0; i < 4; ++i) { \
        acc[(q)*4+i][0] = __builtin_amdgcn_mfma_f32_16x16x32_bf16(Af[i], Bf[0], acc[(q)*4+i][0], 0, 0, 0); \
        acc[(q)*4+i][1] = __builtin_amdgcn_mfma_f32_16x16x32_bf16(Af[i], Bf[1], acc[(q)*4+i][1], 0, 0, 0); \
        acc[(q)*4+i][2] = __builtin_amdgcn_mfma_f32_16x16x32_bf16(Af[i], Bf[2], acc[(q)*4+i][2], 0, 0, 0); \
        acc[(q)*4+i][3] = __builtin_amdgcn_mfma_f32_16x16x32_bf16(Af[i], Bf[3], acc[(q)*4+i][3], 0, 0, 0); \
    } } while (0)

#define PHASE(p, b, sb) do { \
    if constexpr (MODE != 1) { if ((p) < 30) STAGE(sb, ((p) + 2) * 32); } \
    if constexpr (MODE != 2) { \
        LDB4(b); LDA4(b, 0); \
        PRIO1(); MFMA16(0); PRIO0(); \
        LDA4(b, 1); \
        PRIO1(); MFMA16(1); PRIO0(); \
    } \
    if constexpr (MODE != 1) { if ((p) < 30) { VMW4(); } else { VMW0(); } } \
    if ((p) < 31) BAR(); \
} while (0)

    STAGE(0, 0);
    STAGE(1, 32);
    VMW4(); BAR();

    for (int j = 0; j < 10; ++j) {
        PHASE(j * 3 + 0, 0, 2);
        PHASE(j * 3 + 1, 1, 0);
        PHASE(j * 3 + 2, 2, 1);
    }
    PHASE(30, 0, 2);
    PHASE(31, 1, 0);
    if constexpr (MODE == 1) VMW0();   // drain prologue loads before endpgm

    // epilogue: C/D layout col=lane&15, row=(lane>>4)*4+reg
    const int rbase = (lane >> 4) * 4;
    const int cbase = nt * 256 + wn * 64 + (lane & 15);
#pragma unroll
    for (int mi = 0; mi < 8; ++mi) {
#pragma unroll
        for (int r = 0; r < 4; ++r) {
            int slot = mt * 256 + wm * 128 + mi * 16 + rbase + r;
            if (slot < cnt) {
                int lv = lists[listbase + slot];
                u16* crow = contrib + (size_t)lv * DIM + cbase;
#pragma unroll
                for (int ni = 0; ni < 4; ++ni)
                    crow[ni * 16] = f2bf(acc[mi][ni][r]);
            }
        }
    }
}

// out[t] = w0*(c0 + b[e0]) + w1*(c1 + b[e1]); 4 tokens/block
__global__ __launch_bounds__(256) void k_combine(
    const u16* __restrict__ contrib, const float4* __restrict__ selw,
    const float* __restrict__ eb, float* __restrict__ out)
{
    const int lane = threadIdx.x & 63;
    const int t    = blockIdx.x * 4 + (threadIdx.x >> 6);
    float4 sw = selw[t];
    const int e0 = __float_as_int(sw.x);
    const int e1 = __float_as_int(sw.y);
    const float w0 = sw.z, w1 = sw.w;
    const u16* c0 = contrib + (size_t)(t * 2) * DIM;
    const u16* c1 = c0 + DIM;
    const float* b0 = eb + e0 * DIM;
    const float* b1 = eb + e1 * DIM;
    float* orow = out + (size_t)t * DIM;
#pragma unroll
    for (int j = 0; j < 2; ++j) {
        const int c = (j * 64 + lane) * 8;
        uint4 u0 = *reinterpret_cast<const uint4*>(c0 + c);
        uint4 u1 = *reinterpret_cast<const uint4*>(c1 + c);
        const u16* p0 = (const u16*)&u0;
        const u16* p1 = (const u16*)&u1;
#pragma unroll
        for (int h = 0; h < 2; ++h) {
            float4 bb0 = *reinterpret_cast<const float4*>(b0 + c + h * 4);
            float4 bb1 = *reinterpret_cast<const float4*>(b1 + c + h * 4);
            float4 o;
            o.x = w0 * (bf2f(p0[h*4+0]) + bb0.x) + w1 * (bf2f(p1[h*4+0]) + bb1.x);
            o.y = w0 * (bf2f(p0[h*4+1]) + bb0.y) + w1 * (bf2f(p1[h*4+1]) + bb1.y);
            o.z = w0 * (bf2f(p0[h*4+2]) + bb0.z) + w1 * (bf2f(p1[h*4+2]) + bb1.z);
            o.w = w0 * (bf2f(p0[h*4+3]) + bb0.w) + w1 * (bf2f(p1[h*4+3]) + bb1.w);
            *reinterpret_cast<float4*>(orow + c + h * 4) = o;
        }
    }
}

// fallback: bias-init + atomic GEMM when ws too small for contrib
__global__ __launch_bounds__(256) void k_bias(
    const float4* __restrict__ selw, const float* __restrict__ eb,
    float* __restrict__ out)
{
    const int lane = threadIdx.x & 63;
    const int t    = blockIdx.x * 4 + (threadIdx.x >> 6);
    float4 sw = selw[t];
    const float* b0 = eb + __float_as_int(sw.x) * DIM;
    const float* b1 = eb + __float_as_int(sw.y) * DIM;
    float* orow = out + (size_t)t * DIM;
#pragma unroll
    for (int j = 0; j < 4; ++j) {
        int c = (j * 64 + lane) * 4;
        float4 f0 = *reinterpret_cast<const float4*>(b0 + c);
        float4 f1 = *reinterpret_cast<const float4*>(b1 + c);
        float4 o;
        o.x = sw.z * f0.x + sw.w * f1.x;
        o.y = sw.z * f0.y + sw.w * f1.y;
        o.z = sw.z * f0.z + sw.w * f1.z;
        o.w = sw.z * f0.w + sw.w * f1.w;
        *reinterpret_cast<float4*>(orow + c) = o;
    }
}

__global__ __launch_bounds__(256) void k_gemm_atomic(
    const u16* __restrict__ xb, const u16* __restrict__ wb,
    const int* __restrict__ counts, const int* __restrict__ lists,
    const float4* __restrict__ selw, float* __restrict__ out)
{
    // simple fallback (r2-style reg-staged 128x128); correctness path only.
    __shared__ u16 ldsA[128 * 64];
    __shared__ u16 ldsB[128 * 64];
    const int bid = blockIdx.x;
    const int e   = bid >> 10;
    const int mt  = (bid >> 3) & 127;
    const int nt  = bid & 7;
    const int cnt = counts[e * 16];
    if (mt * 128 >= cnt) return;
    const int tid  = threadIdx.x;
    const int lane = tid & 63;
    const int wid  = tid >> 6;
    const int wr   = wid >> 1, wc = wid & 1;
    const int srow = tid >> 3;
    const int skc  = (tid & 7) * 8;
    const int listbase = e * T_TOK;
    int tokA[4];
#pragma unroll
    for (int i = 0; i < 4; ++i) {
        int slot = mt * 128 + i * 32 + srow;
        tokA[i] = lists[listbase + (slot < cnt ? slot : cnt - 1)] >> 1;
    }
    const size_t wbase = ((size_t)e << 20) + (size_t)(nt * 128) * DIM;
    f32x4 acc[4][4];
#pragma unroll
    for (int mi = 0; mi < 4; ++mi)
#pragma unroll
        for (int ni = 0; ni < 4; ++ni) acc[mi][ni] = (f32x4)0.f;
    for (int k0 = 0; k0 < DIM; k0 += 64) {
        uint4 ra[4], rb[4];
#pragma unroll
        for (int i = 0; i < 4; ++i) {
            ra[i] = *reinterpret_cast<const uint4*>(xb + (size_t)tokA[i] * DIM + k0 + skc);
            rb[i] = *reinterpret_cast<const uint4*>(wb + wbase + (size_t)(i * 32 + srow) * DIM + k0 + skc);
        }
        __syncthreads();
#pragma unroll
        for (int i = 0; i < 4; ++i) {
            *reinterpret_cast<uint4*>(ldsA + (i * 32 + srow) * 64 + skc) = ra[i];
            *reinterpret_cast<uint4*>(ldsB + (i * 32 + srow) * 64 + skc) = rb[i];
        }
        __syncthreads();
#pragma unroll
        for (int ks = 0; ks < 2; ++ks) {
            const int kof = ks * 32 + (lane >> 4) * 8;
            bf16x8 af[4], bfr[4];
#pragma unroll
            for (int mi = 0; mi < 4; ++mi)
                af[mi] = *reinterpret_cast<const bf16x8*>(ldsA + (wr * 64 + mi * 16 + (lane & 15)) * 64 + kof);
#pragma unroll
            for (int ni = 0; ni < 4; ++ni)
                bfr[ni] = *reinterpret_cast<const bf16x8*>(ldsB + (wc * 64 + ni * 16 + (lane & 15)) * 64 + kof);
#pragma unroll
            for (int mi = 0; mi < 4; ++mi)
#pragma unroll
                for (int ni = 0; ni < 4; ++ni)
                    acc[mi][ni] = __builtin_amdgcn_mfma_f32_16x16x32_bf16(af[mi], bfr[ni], acc[mi][ni], 0, 0, 0);
        }
        __syncthreads();
    }
    const int rbase = (lane >> 4) * 4;
    const int cbase = nt * 128 + wc * 64 + (lane & 15);
#pragma unroll
    for (int mi = 0; mi < 4; ++mi) {
#pragma unroll
        for (int r = 0; r < 4; ++r) {
            int slot = mt * 128 + wr * 64 + mi * 16 + rbase + r;
            if (slot < cnt) {
                int lv = lists[listbase + slot];
                int tok = lv >> 1;
                float4 sw = selw[tok];
                float wgt = (lv & 1) ? sw.w : sw.z;
                float* orow = out + (size_t)tok * DIM + cbase;
#pragma unroll
                for (int ni = 0; ni < 4; ++ni)
                    atomicAdd(orow + ni * 16, acc[mi][ni][r] * wgt);
            }
        }
    }
}

extern "C" void kernel_launch(void* const* d_in, const int* in_sizes, int n_in,
                              void* d_out, int out_size, void* d_ws, size_t ws_size,
                              hipStream_t stream) {
    const float* x  = (const float*)d_in[0];
    const float* gw = (const float*)d_in[1];
    const float* gb = (const float*)d_in[2];
    const float* ew = (const float*)d_in[3];
    const float* eb = (const float*)d_in[4];

    float* out    = (float*)d_out;
    float* logits = out + (size_t)T_TOK * DIM;

    char*   ws      = (char*)d_ws;
    u16*    xb      = (u16*)(ws + XB_OFF);
    u16*    wb      = (u16*)(ws + WB_OFF);
    int*    counts  = (int*)(ws + CNT_OFF);
    int*    lists   = (int*)(ws + LIST_OFF);
    float4* selw    = (float4*)(ws + SELW_OFF);
    u16*    contrib = (u16*)(ws + CONTRIB_OFF);

    hipMemsetAsync((void*)(ws + CNT_OFF), 0, 512, stream);
    k_router<<<T_TOK / RT_PB, 256, 0, stream>>>(x, gw, gb, logits, xb, counts,
                                                lists, selw, ew, wb);

    const int grid = NEXP * 64 * 4;
    if (ws_size >= WS_NEED) {
        // --- ablation probes (outputs overwritten by MODE 0 below) ---
        k_gemm<2><<<grid, 512, 0, stream>>>(xb, wb, counts, lists, selw, contrib, out);
        k_gemm<1><<<grid, 512, 0, stream>>>(xb, wb, counts, lists, selw, contrib, out);
        // --- real computation ---
        k_gemm<0><<<grid, 512, 0, stream>>>(xb, wb, counts, lists, selw, contrib, out);
        k_combine<<<T_TOK / 4, 256, 0, stream>>>(contrib, selw, eb, out);
    } else {
        k_bias<<<T_TOK / 4, 256, 0, stream>>>(selw, eb, out);
        k_gemm_atomic<<<NEXP * 128 * 8, 256, 0, stream>>>(xb, wb, counts, lists, selw, out);
    }
}

// Round 10
// 214.424 us; speedup vs baseline: 1.5422x; 1.5422x over previous
//
#include <hip/hip_runtime.h>
#include <hip/hip_bf16.h>

typedef unsigned short u16;
typedef unsigned int u32;

#define T_TOK 16384
#define DIM   1024
#define NEXP  8

// ---------- workspace layout (bytes) ----------
#define XB_OFF      0
#define WB_OFF      33554432
#define CNT_OFF     50331648
#define LIST_OFF    50332160
#define SELW_OFF    50856448
#define CONTRIB_OFF 51380736
#define WS_NEED     118489600ULL

__device__ __forceinline__ u16 f2bf(float f) {
    u32 u = __float_as_uint(f);
    u += 0x7fff + ((u >> 16) & 1);   // round-to-nearest-even
    return (u16)(u >> 16);
}
__device__ __forceinline__ float bf2f(u16 u) {
    return __uint_as_float(((u32)u) << 16);
}

// Router + fused expert-weight cvt (unchanged).
#define RT_PB 32

__global__ __launch_bounds__(256) void k_router(
    const float* __restrict__ x, const float* __restrict__ gw,
    const float* __restrict__ gb, float* __restrict__ logits,
    u16* __restrict__ xb, int* __restrict__ counts,
    int* __restrict__ lists, float4* __restrict__ selw,
    const float* __restrict__ ew, u16* __restrict__ wb)
{
    const int tid  = threadIdx.x;
    const int lane = tid & 63;
    const int w    = tid >> 6;

    __shared__ int   s_sel0[RT_PB], s_sel1[RT_PB];
    __shared__ int   s_lcnt[NEXP], s_gbase[NEXP];

    if (tid < NEXP) s_lcnt[tid] = 0;

    for (int i = 0; i < 8; ++i) {
        const int l = w * 8 + i;
        const int t = blockIdx.x * RT_PB + l;

        const float* xr = x + (size_t)t * DIM;
        float4 xs[4];
#pragma unroll
        for (int j = 0; j < 4; ++j)
            xs[j] = *reinterpret_cast<const float4*>(xr + (j * 64 + lane) * 4);

        float acc[NEXP];
#pragma unroll
        for (int e = 0; e < NEXP; ++e) {
            const float* gr = gw + e * DIM;
            float s = 0.f;
#pragma unroll
            for (int j = 0; j < 4; ++j) {
                float4 g = *reinterpret_cast<const float4*>(gr + (j * 64 + lane) * 4);
                s += xs[j].x * g.x + xs[j].y * g.y + xs[j].z * g.z + xs[j].w * g.w;
            }
            acc[e] = s;
        }
#pragma unroll
        for (int off = 1; off < 64; off <<= 1) {
#pragma unroll
            for (int e = 0; e < NEXP; ++e) acc[e] += __shfl_xor(acc[e], off);
        }
#pragma unroll
        for (int e = 0; e < NEXP; ++e) acc[e] += gb[e];

        int i0 = 0; float v0 = acc[0];
#pragma unroll
        for (int e = 1; e < NEXP; ++e) if (acc[e] > v0) { v0 = acc[e]; i0 = e; }
        int i1 = -1; float v1 = -3.4e38f;
#pragma unroll
        for (int e = 0; e < NEXP; ++e) if (e != i0 && acc[e] > v1) { v1 = acc[e]; i1 = e; }
        float e1  = __expf(v1 - v0);
        float inv = 1.f / (1.f + e1);
        float w0 = inv, w1 = e1 * inv;

        u16* xrow = xb + (size_t)t * DIM;
#pragma unroll
        for (int j = 0; j < 4; ++j) {
            int c = (j * 64 + lane) * 4;
            float4 v = xs[j];
            ushort4 u;
            u.x = f2bf(v.x); u.y = f2bf(v.y); u.z = f2bf(v.z); u.w = f2bf(v.w);
            *reinterpret_cast<ushort4*>(xrow + c) = u;
        }
        if (lane == 0) {
            float4 lo = make_float4(acc[0], acc[1], acc[2], acc[3]);
            float4 hi = make_float4(acc[4], acc[5], acc[6], acc[7]);
            *reinterpret_cast<float4*>(logits + (size_t)t * NEXP)     = lo;
            *reinterpret_cast<float4*>(logits + (size_t)t * NEXP + 4) = hi;
            selw[t] = make_float4(__int_as_float(i0), __int_as_float(i1), w0, w1);
            s_sel0[l] = i0; s_sel1[l] = i1;
        }
    }
    __syncthreads();

    int i0 = 0, i1 = 0, r0 = 0, r1 = 0;
    if (tid < RT_PB) {
        i0 = s_sel0[tid]; i1 = s_sel1[tid];
        r0 = atomicAdd(&s_lcnt[i0], 1);
        r1 = atomicAdd(&s_lcnt[i1], 1);
    }
    __syncthreads();
    if (tid < NEXP)
        s_gbase[tid] = atomicAdd(&counts[tid * 16], s_lcnt[tid]);
    __syncthreads();
    if (tid < RT_PB) {
        int t  = blockIdx.x * RT_PB + tid;
        lists[i0 * T_TOK + s_gbase[i0] + r0] = t * 2;
        lists[i1 * T_TOK + s_gbase[i1] + r1] = t * 2 + 1;
    }

    const int n4 = NEXP * DIM * DIM / 4;
    const int stride = gridDim.x * 256;
    for (int i = blockIdx.x * 256 + tid; i < n4; i += stride) {
        float4 v = reinterpret_cast<const float4*>(ew)[i];
        ushort4 u;
        u.x = f2bf(v.x); u.y = f2bf(v.y); u.z = f2bf(v.z); u.w = f2bf(v.w);
        reinterpret_cast<ushort4*>(wb)[i] = u;
    }
}

// ======================= grouped GEMM v5 (r9 ablation-driven):
// A-frags load GLOBAL->REGISTER directly (fragment layout IS the gather:
// lane&15=row, lane>>4=k-chunk), prefetched 1 slice ahead -> no LDS port
// and no lgkm wait on the A path. LDS stages only B (weights, contiguous,
// gload_lds, chunk-rot swizzle, triple-buffered 48 KiB, depth-2). Waves
// re-partitioned to 64x128 tiles (4 wm x 2 wn): A-dup 2x, 8 B ds_reads
// per wave per slice (CU LDS port 768 cyc < 1024 MFMA cyc).
// vmcnt ledger: phase issues B(p+2)x2 then A(p+1)x4; VMW6 at phase end
// leaves exactly those 6, proving all older (incl. B(p+1)) for the next
// phase; robust to intra-phase reorder. Prologue VMW2; tail 4 -> 0.

typedef __attribute__((ext_vector_type(8))) short bf16x8;
typedef __attribute__((ext_vector_type(4))) float f32x4;

#define GLDS16(g, l) __builtin_amdgcn_global_load_lds( \
    (const __attribute__((address_space(1))) void*)(g), \
    (__attribute__((address_space(3))) void*)(l), 16, 0, 0)

#define BAR() __builtin_amdgcn_s_barrier()
#define PRIO1() __builtin_amdgcn_s_setprio(1)
#define PRIO0() __builtin_amdgcn_s_setprio(0)
#define VMW6() asm volatile("s_waitcnt vmcnt(6)" ::: "memory")
#define VMW4() asm volatile("s_waitcnt vmcnt(4)" ::: "memory")
#define VMW2() asm volatile("s_waitcnt vmcnt(2)" ::: "memory")

__global__ __launch_bounds__(512, 2) void k_gemm(
    const u16* __restrict__ xb, const u16* __restrict__ wb,
    const int* __restrict__ counts, const int* __restrict__ lists,
    u16* __restrict__ contrib)
{
    __shared__ u16 lds[24576];   // 48 KiB: 3 B-slice buffers x 16 KB

    // expert->XCD pinning, nt-minor (consecutive blocks share A rows)
    const int bid = (blockIdx.x & 7) * 256 + (blockIdx.x >> 3);
    const int e   = bid >> 8;
    const int mt  = (bid >> 2) & 63;
    const int nt  = bid & 3;
    const int cnt = counts[e * 16];
    if (mt * 256 >= cnt) return;

    const int tid  = threadIdx.x;
    const int lane = tid & 63;
    const int wid  = tid >> 6;
    const int wm   = wid >> 1;   // 0..3 : 64-row block
    const int wn   = wid & 1;    // 0..1 : 128-col block
    const int listbase = e * T_TOK;

    // ---- A: per-lane global gather offsets (fragment layout direct) ----
    const char* xbB = (const char*)xb;
    u32 aoff[4];
#pragma unroll
    for (int mi = 0; mi < 4; ++mi) {
        int slot = mt * 256 + wm * 64 + mi * 16 + (lane & 15);
        int tok  = lists[listbase + (slot < cnt ? slot : cnt - 1)] >> 1;
        aoff[mi] = (u32)tok * (DIM * 2) + (u32)(lane >> 4) * 16;
    }
    bf16x8 aA[4], aB[4];
#define LOADA(dst, s) do { \
    dst[0] = *(const bf16x8*)(xbB + aoff[0] + (s) * 64); \
    dst[1] = *(const bf16x8*)(xbB + aoff[1] + (s) * 64); \
    dst[2] = *(const bf16x8*)(xbB + aoff[2] + (s) * 64); \
    dst[3] = *(const bf16x8*)(xbB + aoff[3] + (s) * 64); } while (0)

    // ---- B staging: row tid>>2 (+128), inverse-swizzled source chunk ----
    const int srow = tid >> 2;
    const int cB   = (((tid & 3) - (tid >> 3)) & 3) * 8;
    const u16* srcB0 = wb + ((size_t)e << 20) + (size_t)(nt * 256 + srow) * DIM + cB;
    const u16* srcB1 = srcB0 + (size_t)128 * DIM;
#define STAGE_B(b, kk) do { \
    GLDS16(srcB0 + (kk), &lds[(b) * 8192 + wid * 512]); \
    GLDS16(srcB1 + (kk), &lds[(b) * 8192 + 4096 + wid * 512]); } while (0)

    // ---- B read: row r, chunk c=lane>>4 stored at slot (c+(r>>1))&3 ----
    const int cs8  = (((lane >> 4) + ((lane >> 1) & 3)) & 3) * 8;
    const int offB = (wn * 128 + (lane & 15)) * 32 + cs8;

    bf16x8 Bf[8];
#define LDB8(bc) do { \
    _Pragma("unroll") \
    for (int ni = 0; ni < 8; ++ni) \
        Bf[ni] = *(const bf16x8*)&lds[(bc) * 8192 + ni * 512 + offB]; } while (0)

    f32x4 acc[4][8];
#pragma unroll
    for (int mi = 0; mi < 4; ++mi)
#pragma unroll
        for (int ni = 0; ni < 8; ++ni) acc[mi][ni] = (f32x4)0.f;

#define MFMA32(a) do { \
    _Pragma("unroll") \
    for (int mi = 0; mi < 4; ++mi) { \
        _Pragma("unroll") \
        for (int ni = 0; ni < 8; ++ni) \
            acc[mi][ni] = __builtin_amdgcn_mfma_f32_16x16x32_bf16((a)[mi], Bf[ni], acc[mi][ni], 0, 0, 0); \
    } } while (0)

    // prologue: A(0)->aA; B slices 0,1 into bufs 0,1; prove A(0),B(0).
    LOADA(aA, 0);
    STAGE_B(0, 0);
    STAGE_B(1, 32);
    VMW2(); BAR();

    int bc = 0;                       // buffer of current slice (p % 3)
    for (int h = 0; h < 15; ++h) {    // phases p0=2h (0..28), p1=2h+1 (1..29)
        const int p0 = 2 * h;
        const int bs0 = bc >= 1 ? bc - 1 : 2;      // (bc+2)%3
        STAGE_B(bs0, (p0 + 2) * 32);
        LOADA(aB, p0 + 1);
        LDB8(bc);
        PRIO1(); MFMA32(aA); PRIO0();
        VMW6(); BAR();
        const int bc1 = bc == 2 ? 0 : bc + 1;
        const int bs1 = bc1 >= 1 ? bc1 - 1 : 2;
        STAGE_B(bs1, (p0 + 3) * 32);
        LOADA(aA, p0 + 2);
        LDB8(bc1);
        PRIO1(); MFMA32(aB); PRIO0();
        VMW6(); BAR();
        bc = bc1 == 2 ? 0 : bc1 + 1;
    }
    {   // p=30 (buf 0): no stage; prefetch A(31)
        LOADA(aB, 31);
        LDB8(0);
        PRIO1(); MFMA32(aA); PRIO0();
        VMW4(); BAR();
        // p=31 (buf 1): final
        LDB8(1);
        PRIO1(); MFMA32(aB); PRIO0();
    }

    // epilogue: C/D layout col=lane&15, row=(lane>>4)*4+reg
    const int rbase = (lane >> 4) * 4;
    const int cbase = nt * 256 + wn * 128 + (lane & 15);
#pragma unroll
    for (int mi = 0; mi < 4; ++mi) {
#pragma unroll
        for (int r = 0; r < 4; ++r) {
            int slot = mt * 256 + wm * 64 + mi * 16 + rbase + r;
            if (slot < cnt) {
                int lv = lists[listbase + slot];
                u16* crow = contrib + (size_t)lv * DIM + cbase;
#pragma unroll
                for (int ni = 0; ni < 8; ++ni)
                    crow[ni * 16] = f2bf(acc[mi][ni][r]);
            }
        }
    }
}

// out[t] = w0*(c0 + b[e0]) + w1*(c1 + b[e1]); 4 tokens/block
__global__ __launch_bounds__(256) void k_combine(
    const u16* __restrict__ contrib, const float4* __restrict__ selw,
    const float* __restrict__ eb, float* __restrict__ out)
{
    const int lane = threadIdx.x & 63;
    const int t    = blockIdx.x * 4 + (threadIdx.x >> 6);
    float4 sw = selw[t];
    const int e0 = __float_as_int(sw.x);
    const int e1 = __float_as_int(sw.y);
    const float w0 = sw.z, w1 = sw.w;
    const u16* c0 = contrib + (size_t)(t * 2) * DIM;
    const u16* c1 = c0 + DIM;
    const float* b0 = eb + e0 * DIM;
    const float* b1 = eb + e1 * DIM;
    float* orow = out + (size_t)t * DIM;
#pragma unroll
    for (int j = 0; j < 2; ++j) {
        const int c = (j * 64 + lane) * 8;
        uint4 u0 = *reinterpret_cast<const uint4*>(c0 + c);
        uint4 u1 = *reinterpret_cast<const uint4*>(c1 + c);
        const u16* p0 = (const u16*)&u0;
        const u16* p1 = (const u16*)&u1;
#pragma unroll
        for (int h = 0; h < 2; ++h) {
            float4 bb0 = *reinterpret_cast<const float4*>(b0 + c + h * 4);
            float4 bb1 = *reinterpret_cast<const float4*>(b1 + c + h * 4);
            float4 o;
            o.x = w0 * (bf2f(p0[h*4+0]) + bb0.x) + w1 * (bf2f(p1[h*4+0]) + bb1.x);
            o.y = w0 * (bf2f(p0[h*4+1]) + bb0.y) + w1 * (bf2f(p1[h*4+1]) + bb1.y);
            o.z = w0 * (bf2f(p0[h*4+2]) + bb0.z) + w1 * (bf2f(p1[h*4+2]) + bb1.z);
            o.w = w0 * (bf2f(p0[h*4+3]) + bb0.w) + w1 * (bf2f(p1[h*4+3]) + bb1.w);
            *reinterpret_cast<float4*>(orow + c + h * 4) = o;
        }
    }
}

// fallback: bias-init + atomic GEMM when ws too small for contrib
__global__ __launch_bounds__(256) void k_bias(
    const float4* __restrict__ selw, const float* __restrict__ eb,
    float* __restrict__ out)
{
    const int lane = threadIdx.x & 63;
    const int t    = blockIdx.x * 4 + (threadIdx.x >> 6);
    float4 sw = selw[t];
    const float* b0 = eb + __float_as_int(sw.x) * DIM;
    const float* b1 = eb + __float_as_int(sw.y) * DIM;
    float* orow = out + (size_t)t * DIM;
#pragma unroll
    for (int j = 0; j < 4; ++j) {
        int c = (j * 64 + lane) * 4;
        float4 f0 = *reinterpret_cast<const float4*>(b0 + c);
        float4 f1 = *reinterpret_cast<const float4*>(b1 + c);
        float4 o;
        o.x = sw.z * f0.x + sw.w * f1.x;
        o.y = sw.z * f0.y + sw.w * f1.y;
        o.z = sw.z * f0.z + sw.w * f1.z;
        o.w = sw.z * f0.w + sw.w * f1.w;
        *reinterpret_cast<float4*>(orow + c) = o;
    }
}

__global__ __launch_bounds__(256) void k_gemm_atomic(
    const u16* __restrict__ xb, const u16* __restrict__ wb,
    const int* __restrict__ counts, const int* __restrict__ lists,
    const float4* __restrict__ selw, float* __restrict__ out)
{
    __shared__ u16 ldsA[128 * 64];
    __shared__ u16 ldsB[128 * 64];
    const int bid = blockIdx.x;
    const int e   = bid >> 10;
    const int mt  = (bid >> 3) & 127;
    const int nt  = bid & 7;
    const int cnt = counts[e * 16];
    if (mt * 128 >= cnt) return;
    const int tid  = threadIdx.x;
    const int lane = tid & 63;
    const int wid  = tid >> 6;
    const int wr   = wid >> 1, wc = wid & 1;
    const int srow = tid >> 3;
    const int skc  = (tid & 7) * 8;
    const int listbase = e * T_TOK;
    int tokA[4];
#pragma unroll
    for (int i = 0; i < 4; ++i) {
        int slot = mt * 128 + i * 32 + srow;
        tokA[i] = lists[listbase + (slot < cnt ? slot : cnt - 1)] >> 1;
    }
    const size_t wbase = ((size_t)e << 20) + (size_t)(nt * 128) * DIM;
    f32x4 acc[4][4];
#pragma unroll
    for (int mi = 0; mi < 4; ++mi)
#pragma unroll
        for (int ni = 0; ni < 4; ++ni) acc[mi][ni] = (f32x4)0.f;
    for (int k0 = 0; k0 < DIM; k0 += 64) {
        uint4 ra[4], rb[4];
#pragma unroll
        for (int i = 0; i < 4; ++i) {
            ra[i] = *reinterpret_cast<const uint4*>(xb + (size_t)tokA[i] * DIM + k0 + skc);
            rb[i] = *reinterpret_cast<const uint4*>(wb + wbase + (size_t)(i * 32 + srow) * DIM + k0 + skc);
        }
        __syncthreads();
#pragma unroll
        for (int i = 0; i < 4; ++i) {
            *reinterpret_cast<uint4*>(ldsA + (i * 32 + srow) * 64 + skc) = ra[i];
            *reinterpret_cast<uint4*>(ldsB + (i * 32 + srow) * 64 + skc) = rb[i];
        }
        __syncthreads();
#pragma unroll
        for (int ks = 0; ks < 2; ++ks) {
            const int kof = ks * 32 + (lane >> 4) * 8;
            bf16x8 af[4], bfr[4];
#pragma unroll
            for (int mi = 0; mi < 4; ++mi)
                af[mi] = *reinterpret_cast<const bf16x8*>(ldsA + (wr * 64 + mi * 16 + (lane & 15)) * 64 + kof);
#pragma unroll
            for (int ni = 0; ni < 4; ++ni)
                bfr[ni] = *reinterpret_cast<const bf16x8*>(ldsB + (wc * 64 + ni * 16 + (lane & 15)) * 64 + kof);
#pragma unroll
            for (int mi = 0; mi < 4; ++mi)
#pragma unroll
                for (int ni = 0; ni < 4; ++ni)
                    acc[mi][ni] = __builtin_amdgcn_mfma_f32_16x16x32_bf16(af[mi], bfr[ni], acc[mi][ni], 0, 0, 0);
        }
        __syncthreads();
    }
    const int rbase = (lane >> 4) * 4;
    const int cbase = nt * 128 + wc * 64 + (lane & 15);
#pragma unroll
    for (int mi = 0; mi < 4; ++mi) {
#pragma unroll
        for (int r = 0; r < 4; ++r) {
            int slot = mt * 128 + wr * 64 + mi * 16 + rbase + r;
            if (slot < cnt) {
                int lv = lists[listbase + slot];
                int tok = lv >> 1;
                float4 sw = selw[tok];
                float wgt = (lv & 1) ? sw.w : sw.z;
                float* orow = out + (size_t)tok * DIM + cbase;
#pragma unroll
                for (int ni = 0; ni < 4; ++ni)
                    atomicAdd(orow + ni * 16, acc[mi][ni][r] * wgt);
            }
        }
    }
}

extern "C" void kernel_launch(void* const* d_in, const int* in_sizes, int n_in,
                              void* d_out, int out_size, void* d_ws, size_t ws_size,
                              hipStream_t stream) {
    const float* x  = (const float*)d_in[0];
    const float* gw = (const float*)d_in[1];
    const float* gb = (const float*)d_in[2];
    const float* ew = (const float*)d_in[3];
    const float* eb = (const float*)d_in[4];

    float* out    = (float*)d_out;
    float* logits = out + (size_t)T_TOK * DIM;

    char*   ws      = (char*)d_ws;
    u16*    xb      = (u16*)(ws + XB_OFF);
    u16*    wb      = (u16*)(ws + WB_OFF);
    int*    counts  = (int*)(ws + CNT_OFF);
    int*    lists   = (int*)(ws + LIST_OFF);
    float4* selw    = (float4*)(ws + SELW_OFF);
    u16*    contrib = (u16*)(ws + CONTRIB_OFF);

    hipMemsetAsync((void*)(ws + CNT_OFF), 0, 512, stream);
    k_router<<<T_TOK / RT_PB, 256, 0, stream>>>(x, gw, gb, logits, xb, counts,
                                                lists, selw, ew, wb);

    if (ws_size >= WS_NEED) {
        k_gemm<<<NEXP * 64 * 4, 512, 0, stream>>>(xb, wb, counts, lists, contrib);
        k_combine<<<T_TOK / 4, 256, 0, stream>>>(contrib, selw, eb, out);
    } else {
        k_bias<<<T_TOK / 4, 256, 0, stream>>>(selw, eb, out);
        k_gemm_atomic<<<NEXP * 128 * 8, 256, 0, stream>>>(xb, wb, counts, lists, selw, out);
    }
}

// Round 11
// 174.481 us; speedup vs baseline: 1.8953x; 1.2289x over previous
//
#include <hip/hip_runtime.h>
#include <hip/hip_bf16.h>

typedef unsigned short u16;
typedef unsigned int u32;

#define T_TOK 16384
#define DIM   1024
#define NEXP  8

// ---------- workspace layout (bytes) ----------
#define XB_OFF      0
#define WB_OFF      33554432
#define CNT_OFF     50331648
#define LIST_OFF    50332160
#define SELW_OFF    50856448
#define CONTRIB_OFF 51380736
#define WS_NEED     118489600ULL

__device__ __forceinline__ u16 f2bf(float f) {
    u32 u = __float_as_uint(f);
    u += 0x7fff + ((u >> 16) & 1);   // round-to-nearest-even
    return (u16)(u >> 16);
}
__device__ __forceinline__ float bf2f(u16 u) {
    return __uint_as_float(((u32)u) << 16);
}

// Router + fused expert-weight cvt (unchanged).
#define RT_PB 32

__global__ __launch_bounds__(256) void k_router(
    const float* __restrict__ x, const float* __restrict__ gw,
    const float* __restrict__ gb, float* __restrict__ logits,
    u16* __restrict__ xb, int* __restrict__ counts,
    int* __restrict__ lists, float4* __restrict__ selw,
    const float* __restrict__ ew, u16* __restrict__ wb)
{
    const int tid  = threadIdx.x;
    const int lane = tid & 63;
    const int w    = tid >> 6;

    __shared__ int   s_sel0[RT_PB], s_sel1[RT_PB];
    __shared__ int   s_lcnt[NEXP], s_gbase[NEXP];

    if (tid < NEXP) s_lcnt[tid] = 0;

    for (int i = 0; i < 8; ++i) {
        const int l = w * 8 + i;
        const int t = blockIdx.x * RT_PB + l;

        const float* xr = x + (size_t)t * DIM;
        float4 xs[4];
#pragma unroll
        for (int j = 0; j < 4; ++j)
            xs[j] = *reinterpret_cast<const float4*>(xr + (j * 64 + lane) * 4);

        float acc[NEXP];
#pragma unroll
        for (int e = 0; e < NEXP; ++e) {
            const float* gr = gw + e * DIM;
            float s = 0.f;
#pragma unroll
            for (int j = 0; j < 4; ++j) {
                float4 g = *reinterpret_cast<const float4*>(gr + (j * 64 + lane) * 4);
                s += xs[j].x * g.x + xs[j].y * g.y + xs[j].z * g.z + xs[j].w * g.w;
            }
            acc[e] = s;
        }
#pragma unroll
        for (int off = 1; off < 64; off <<= 1) {
#pragma unroll
            for (int e = 0; e < NEXP; ++e) acc[e] += __shfl_xor(acc[e], off);
        }
#pragma unroll
        for (int e = 0; e < NEXP; ++e) acc[e] += gb[e];

        int i0 = 0; float v0 = acc[0];
#pragma unroll
        for (int e = 1; e < NEXP; ++e) if (acc[e] > v0) { v0 = acc[e]; i0 = e; }
        int i1 = -1; float v1 = -3.4e38f;
#pragma unroll
        for (int e = 0; e < NEXP; ++e) if (e != i0 && acc[e] > v1) { v1 = acc[e]; i1 = e; }
        float e1  = __expf(v1 - v0);
        float inv = 1.f / (1.f + e1);
        float w0 = inv, w1 = e1 * inv;

        u16* xrow = xb + (size_t)t * DIM;
#pragma unroll
        for (int j = 0; j < 4; ++j) {
            int c = (j * 64 + lane) * 4;
            float4 v = xs[j];
            ushort4 u;
            u.x = f2bf(v.x); u.y = f2bf(v.y); u.z = f2bf(v.z); u.w = f2bf(v.w);
            *reinterpret_cast<ushort4*>(xrow + c) = u;
        }
        if (lane == 0) {
            float4 lo = make_float4(acc[0], acc[1], acc[2], acc[3]);
            float4 hi = make_float4(acc[4], acc[5], acc[6], acc[7]);
            *reinterpret_cast<float4*>(logits + (size_t)t * NEXP)     = lo;
            *reinterpret_cast<float4*>(logits + (size_t)t * NEXP + 4) = hi;
            selw[t] = make_float4(__int_as_float(i0), __int_as_float(i1), w0, w1);
            s_sel0[l] = i0; s_sel1[l] = i1;
        }
    }
    __syncthreads();

    int i0 = 0, i1 = 0, r0 = 0, r1 = 0;
    if (tid < RT_PB) {
        i0 = s_sel0[tid]; i1 = s_sel1[tid];
        r0 = atomicAdd(&s_lcnt[i0], 1);
        r1 = atomicAdd(&s_lcnt[i1], 1);
    }
    __syncthreads();
    if (tid < NEXP)
        s_gbase[tid] = atomicAdd(&counts[tid * 16], s_lcnt[tid]);
    __syncthreads();
    if (tid < RT_PB) {
        int t  = blockIdx.x * RT_PB + tid;
        lists[i0 * T_TOK + s_gbase[i0] + r0] = t * 2;
        lists[i1 * T_TOK + s_gbase[i1] + r1] = t * 2 + 1;
    }

    const int n4 = NEXP * DIM * DIM / 4;
    const int stride = gridDim.x * 256;
    for (int i = blockIdx.x * 256 + tid; i < n4; i += stride) {
        float4 v = reinterpret_cast<const float4*>(ew)[i];
        ushort4 u;
        u.x = f2bf(v.x); u.y = f2bf(v.y); u.z = f2bf(v.z); u.w = f2bf(v.w);
        reinterpret_cast<ushort4*>(wb)[i] = u;
    }
}

// ======================= grouped GEMM v6: m201 8-phase port.
// 256x256 tile, 8 waves (2M x 4N), 2 K-tile buffers (A+B, 128 KiB),
// 4 phases per K-tile. Phase q: {ds_read A-band q (4 b128; ph0 also all
// B, 8 b128, held in regs); stage 2 bands via gload_lds; BAR; lgkmcnt(0)+
// sched_barrier; setprio1; 16 MFMA; setprio0; [ph3: vmcnt(6)]; BAR}.
// Band-major LDS (8KB bands) makes each stage target a region freed one
// phase earlier (WAR-safe via barriers). vmcnt ledger: steady 14 in
// flight at ph3 wait -> vmcnt(6) proves next K-tile's 8; t=14 drains.
// 8-slot chunk-rotation swizzle: slot=(chunk+row)&7 (2 lanes/slot = free).

typedef __attribute__((ext_vector_type(8))) short bf16x8;
typedef __attribute__((ext_vector_type(4))) float f32x4;

#define GLDS16(g, l) __builtin_amdgcn_global_load_lds( \
    (const __attribute__((address_space(1))) void*)(g), \
    (__attribute__((address_space(3))) void*)(l), 16, 0, 0)

#define BAR() __builtin_amdgcn_s_barrier()
#define PRIO1() __builtin_amdgcn_s_setprio(1)
#define PRIO0() __builtin_amdgcn_s_setprio(0)
#define VMW6() asm volatile("s_waitcnt vmcnt(6)" ::: "memory")
#define VMW0() asm volatile("s_waitcnt vmcnt(0)" ::: "memory")
#define LGKM0() do { asm volatile("s_waitcnt lgkmcnt(0)" ::: "memory"); \
                     __builtin_amdgcn_sched_barrier(0); } while (0)

__global__ __launch_bounds__(512, 2) void k_gemm(
    const u16* __restrict__ xb, const u16* __restrict__ wb,
    const int* __restrict__ counts, const int* __restrict__ lists,
    u16* __restrict__ contrib)
{
    __shared__ u16 lds[65536];   // 128 KiB: buf b*32768 | A bands q*4096 | B +16384 bands g*4096

    // expert->XCD pinning, nt-minor
    const int bid = (blockIdx.x & 7) * 256 + (blockIdx.x >> 3);
    const int e   = bid >> 8;
    const int mt  = (bid >> 2) & 63;
    const int nt  = bid & 3;
    const int cnt = counts[e * 16];
    if (mt * 256 >= cnt) return;

    const int tid  = threadIdx.x;
    const int lane = tid & 63;
    const int wid  = tid >> 6;
    const int wm   = wid >> 2;   // 0..1
    const int wn   = wid & 3;    // 0..3
    const int listbase = e * T_TOK;

    // ---- staging maps (band = 64 rows x 64 k, 8KB; 1 gload/thread) ----
    // thread covers band-local row lr=tid>>3, slot s=tid&7 (16B each);
    // slot s holds source chunk cg=(s-lr)&7. LDS dest linear = tid*16B.
    const int lr = tid >> 3;
    const int cg = ((tid & 7) - lr) & 7;
    // A band q: global rows q*32+(lr&31) (+128 if lr>=32)
    u32 srcAoff[4];
#pragma unroll
    for (int q = 0; q < 4; ++q) {
        int slot = mt * 256 + q * 32 + (lr & 31) + ((lr >> 5) << 7);
        int tok  = lists[listbase + (slot < cnt ? slot : cnt - 1)] >> 1;
        srcAoff[q] = (u32)tok * 2048 + (u32)cg * 16;
    }
    // B band g: W rows nt*256 + g*64 + lr
    u32 srcBoff[4];
#pragma unroll
    for (int g = 0; g < 4; ++g)
        srcBoff[g] = ((u32)e << 21) + (u32)(nt * 256 + g * 64 + lr) * 2048 + (u32)cg * 16;

    const char* xbB = (const char*)xb;
    const char* wbB = (const char*)wb;

#define STG_A(bb, q, tp) GLDS16(xbB + srcAoff[q] + (tp) * 128, \
                                &lds[(bb) * 32768 + (q) * 4096 + tid * 8])
#define STG_B(bb, g, tp) GLDS16(wbB + srcBoff[g] + (tp) * 128, \
                                &lds[(bb) * 32768 + 16384 + (g) * 4096 + tid * 8])

    // ---- read offsets (u16 units, within buf) ----
    // A frag (q, j, kk): band q, local row rj=wm*32+j*16+(lane&15),
    // chunk ckk=kk*4+(lane>>4), slot (ckk+rj)&7.
    const int l15 = lane & 15;
    const int c0  = lane >> 4;
    int aoff[2][2], boff[4][2];
#pragma unroll
    for (int j = 0; j < 2; ++j) {
        int rj = wm * 32 + j * 16 + l15;
#pragma unroll
        for (int kk = 0; kk < 2; ++kk)
            aoff[j][kk] = rj * 64 + (((kk * 4 + c0) + rj) & 7) * 8;
    }
#pragma unroll
    for (int ni = 0; ni < 4; ++ni) {
        int rb = ni * 16 + l15;
#pragma unroll
        for (int kk = 0; kk < 2; ++kk)
            boff[ni][kk] = 16384 + wn * 4096 + rb * 64 + (((kk * 4 + c0) + rb) & 7) * 8;
    }

    bf16x8 aF[4];      // [j*2+kk] for current phase's band
    bf16x8 Bf[8];      // [ni*2+kk] held across the K-tile
    f32x4 acc[8][4];
#pragma unroll
    for (int mi = 0; mi < 8; ++mi)
#pragma unroll
        for (int ni = 0; ni < 4; ++ni) acc[mi][ni] = (f32x4)0.f;

#define LDB_ALL(bb) do { \
    _Pragma("unroll") \
    for (int ni = 0; ni < 4; ++ni) { \
        Bf[ni * 2 + 0] = *(const bf16x8*)&lds[(bb) * 32768 + boff[ni][0]]; \
        Bf[ni * 2 + 1] = *(const bf16x8*)&lds[(bb) * 32768 + boff[ni][1]]; \
    } } while (0)
#define LDA_PH(bb, q) do { \
    aF[0] = *(const bf16x8*)&lds[(bb) * 32768 + (q) * 4096 + aoff[0][0]]; \
    aF[1] = *(const bf16x8*)&lds[(bb) * 32768 + (q) * 4096 + aoff[0][1]]; \
    aF[2] = *(const bf16x8*)&lds[(bb) * 32768 + (q) * 4096 + aoff[1][0]]; \
    aF[3] = *(const bf16x8*)&lds[(bb) * 32768 + (q) * 4096 + aoff[1][1]]; } while (0)
#define MFMA_PH(q) do { \
    _Pragma("unroll") \
    for (int j = 0; j < 2; ++j) { \
        _Pragma("unroll") \
        for (int kk = 0; kk < 2; ++kk) { \
            _Pragma("unroll") \
            for (int ni = 0; ni < 4; ++ni) \
                acc[2 * (q) + j][ni] = __builtin_amdgcn_mfma_f32_16x16x32_bf16( \
                    aF[j * 2 + kk], Bf[ni * 2 + kk], acc[2 * (q) + j][ni], 0, 0, 0); \
        } } } while (0)

// Phase macro. Stage schedule (all regions freed one phase earlier):
//  ph0: A-bands 2,3 of K-tile t+1 -> buf b^1   (iff 1<=t<=14)
//  ph1: B-bands 0,1 of K-tile t+2 -> buf b     (iff t<=13)
//  ph2: B-bands 2,3 of t+2                      (iff t<=13)
//  ph3: A-bands 0,1 of t+2                      (iff t<=13); vmcnt
#define PH(t, b, q) do { \
    if ((q) == 0) LDB_ALL(b); \
    LDA_PH(b, q); \
    if ((q) == 0) { if ((t) >= 1 && (t) <= 14) { STG_A((b) ^ 1, 2, (t) + 1); STG_A((b) ^ 1, 3, (t) + 1); } } \
    else if ((q) == 1) { if ((t) <= 13) { STG_B(b, 0, (t) + 2); STG_B(b, 1, (t) + 2); } } \
    else if ((q) == 2) { if ((t) <= 13) { STG_B(b, 2, (t) + 2); STG_B(b, 3, (t) + 2); } } \
    else               { if ((t) <= 13) { STG_A(b, 0, (t) + 2); STG_A(b, 1, (t) + 2); } } \
    BAR(); \
    LGKM0(); \
    PRIO1(); MFMA_PH(q); PRIO0(); \
    if ((q) == 3) { if ((t) <= 13) { VMW6(); } else if ((t) == 14) { VMW0(); } } \
    BAR(); \
} while (0)

    // prologue: stage K-tiles 0 (buf0) and 1 (buf1) fully
#pragma unroll
    for (int q = 0; q < 4; ++q) { STG_A(0, q, 0); STG_B(0, q, 0); }
#pragma unroll
    for (int q = 0; q < 4; ++q) { STG_A(1, q, 1); STG_B(1, q, 1); }
    VMW0(); BAR();

    for (int t = 0; t < 16; ++t) {
        const int b = t & 1;
        PH(t, b, 0);
        PH(t, b, 1);
        PH(t, b, 2);
        PH(t, b, 3);
    }

    // epilogue: C/D layout col=lane&15, row=(lane>>4)*4+reg
    const int rbase = (lane >> 4) * 4;
    const int cbase = nt * 256 + wn * 64 + l15;
#pragma unroll
    for (int mi = 0; mi < 8; ++mi) {
#pragma unroll
        for (int r = 0; r < 4; ++r) {
            int slot = mt * 256 + wm * 128 + mi * 16 + rbase + r;
            if (slot < cnt) {
                int lv = lists[listbase + slot];
                u16* crow = contrib + (size_t)lv * DIM + cbase;
#pragma unroll
                for (int ni = 0; ni < 4; ++ni)
                    crow[ni * 16] = f2bf(acc[mi][ni][r]);
            }
        }
    }
}

// out[t] = w0*(c0 + b[e0]) + w1*(c1 + b[e1]); 4 tokens/block
__global__ __launch_bounds__(256) void k_combine(
    const u16* __restrict__ contrib, const float4* __restrict__ selw,
    const float* __restrict__ eb, float* __restrict__ out)
{
    const int lane = threadIdx.x & 63;
    const int t    = blockIdx.x * 4 + (threadIdx.x >> 6);
    float4 sw = selw[t];
    const int e0 = __float_as_int(sw.x);
    const int e1 = __float_as_int(sw.y);
    const float w0 = sw.z, w1 = sw.w;
    const u16* c0 = contrib + (size_t)(t * 2) * DIM;
    const u16* c1 = c0 + DIM;
    const float* b0 = eb + e0 * DIM;
    const float* b1 = eb + e1 * DIM;
    float* orow = out + (size_t)t * DIM;
#pragma unroll
    for (int j = 0; j < 2; ++j) {
        const int c = (j * 64 + lane) * 8;
        uint4 u0 = *reinterpret_cast<const uint4*>(c0 + c);
        uint4 u1 = *reinterpret_cast<const uint4*>(c1 + c);
        const u16* p0 = (const u16*)&u0;
        const u16* p1 = (const u16*)&u1;
#pragma unroll
        for (int h = 0; h < 2; ++h) {
            float4 bb0 = *reinterpret_cast<const float4*>(b0 + c + h * 4);
            float4 bb1 = *reinterpret_cast<const float4*>(b1 + c + h * 4);
            float4 o;
            o.x = w0 * (bf2f(p0[h*4+0]) + bb0.x) + w1 * (bf2f(p1[h*4+0]) + bb1.x);
            o.y = w0 * (bf2f(p0[h*4+1]) + bb0.y) + w1 * (bf2f(p1[h*4+1]) + bb1.y);
            o.z = w0 * (bf2f(p0[h*4+2]) + bb0.z) + w1 * (bf2f(p1[h*4+2]) + bb1.z);
            o.w = w0 * (bf2f(p0[h*4+3]) + bb0.w) + w1 * (bf2f(p1[h*4+3]) + bb1.w);
            *reinterpret_cast<float4*>(orow + c + h * 4) = o;
        }
    }
}

// fallback: bias-init + atomic GEMM when ws too small for contrib
__global__ __launch_bounds__(256) void k_bias(
    const float4* __restrict__ selw, const float* __restrict__ eb,
    float* __restrict__ out)
{
    const int lane = threadIdx.x & 63;
    const int t    = blockIdx.x * 4 + (threadIdx.x >> 6);
    float4 sw = selw[t];
    const float* b0 = eb + __float_as_int(sw.x) * DIM;
    const float* b1 = eb + __float_as_int(sw.y) * DIM;
    float* orow = out + (size_t)t * DIM;
#pragma unroll
    for (int j = 0; j < 4; ++j) {
        int c = (j * 64 + lane) * 4;
        float4 f0 = *reinterpret_cast<const float4*>(b0 + c);
        float4 f1 = *reinterpret_cast<const float4*>(b1 + c);
        float4 o;
        o.x = sw.z * f0.x + sw.w * f1.x;
        o.y = sw.z * f0.y + sw.w * f1.y;
        o.z = sw.z * f0.z + sw.w * f1.z;
        o.w = sw.z * f0.w + sw.w * f1.w;
        *reinterpret_cast<float4*>(orow + c) = o;
    }
}

__global__ __launch_bounds__(256) void k_gemm_atomic(
    const u16* __restrict__ xb, const u16* __restrict__ wb,
    const int* __restrict__ counts, const int* __restrict__ lists,
    const float4* __restrict__ selw, float* __restrict__ out)
{
    __shared__ u16 ldsA[128 * 64];
    __shared__ u16 ldsB[128 * 64];
    const int bid = blockIdx.x;
    const int e   = bid >> 10;
    const int mt  = (bid >> 3) & 127;
    const int nt  = bid & 7;
    const int cnt = counts[e * 16];
    if (mt * 128 >= cnt) return;
    const int tid  = threadIdx.x;
    const int lane = tid & 63;
    const int wid  = tid >> 6;
    const int wr   = wid >> 1, wc = wid & 1;
    const int srow = tid >> 3;
    const int skc  = (tid & 7) * 8;
    const int listbase = e * T_TOK;
    int tokA[4];
#pragma unroll
    for (int i = 0; i < 4; ++i) {
        int slot = mt * 128 + i * 32 + srow;
        tokA[i] = lists[listbase + (slot < cnt ? slot : cnt - 1)] >> 1;
    }
    const size_t wbase = ((size_t)e << 20) + (size_t)(nt * 128) * DIM;
    f32x4 acc[4][4];
#pragma unroll
    for (int mi = 0; mi < 4; ++mi)
#pragma unroll
        for (int ni = 0; ni < 4; ++ni) acc[mi][ni] = (f32x4)0.f;
    for (int k0 = 0; k0 < DIM; k0 += 64) {
        uint4 ra[4], rb[4];
#pragma unroll
        for (int i = 0; i < 4; ++i) {
            ra[i] = *reinterpret_cast<const uint4*>(xb + (size_t)tokA[i] * DIM + k0 + skc);
            rb[i] = *reinterpret_cast<const uint4*>(wb + wbase + (size_t)(i * 32 + srow) * DIM + k0 + skc);
        }
        __syncthreads();
#pragma unroll
        for (int i = 0; i < 4; ++i) {
            *reinterpret_cast<uint4*>(ldsA + (i * 32 + srow) * 64 + skc) = ra[i];
            *reinterpret_cast<uint4*>(ldsB + (i * 32 + srow) * 64 + skc) = rb[i];
        }
        __syncthreads();
#pragma unroll
        for (int ks = 0; ks < 2; ++ks) {
            const int kof = ks * 32 + (lane >> 4) * 8;
            bf16x8 af[4], bfr[4];
#pragma unroll
            for (int mi = 0; mi < 4; ++mi)
                af[mi] = *reinterpret_cast<const bf16x8*>(ldsA + (wr * 64 + mi * 16 + (lane & 15)) * 64 + kof);
#pragma unroll
            for (int ni = 0; ni < 4; ++ni)
                bfr[ni] = *reinterpret_cast<const bf16x8*>(ldsB + (wc * 64 + ni * 16 + (lane & 15)) * 64 + kof);
#pragma unroll
            for (int mi = 0; mi < 4; ++mi)
#pragma unroll
                for (int ni = 0; ni < 4; ++ni)
                    acc[mi][ni] = __builtin_amdgcn_mfma_f32_16x16x32_bf16(af[mi], bfr[ni], acc[mi][ni], 0, 0, 0);
        }
        __syncthreads();
    }
    const int rbase = (lane >> 4) * 4;
    const int cbase = nt * 128 + wc * 64 + (lane & 15);
#pragma unroll
    for (int mi = 0; mi < 4; ++mi) {
#pragma unroll
        for (int r = 0; r < 4; ++r) {
            int slot = mt * 128 + wr * 64 + mi * 16 + rbase + r;
            if (slot < cnt) {
                int lv = lists[listbase + slot];
                int tok = lv >> 1;
                float4 sw = selw[tok];
                float wgt = (lv & 1) ? sw.w : sw.z;
                float* orow = out + (size_t)tok * DIM + cbase;
#pragma unroll
                for (int ni = 0; ni < 4; ++ni)
                    atomicAdd(orow + ni * 16, acc[mi][ni][r] * wgt);
            }
        }
    }
}

extern "C" void kernel_launch(void* const* d_in, const int* in_sizes, int n_in,
                              void* d_out, int out_size, void* d_ws, size_t ws_size,
                              hipStream_t stream) {
    const float* x  = (const float*)d_in[0];
    const float* gw = (const float*)d_in[1];
    const float* gb = (const float*)d_in[2];
    const float* ew = (const float*)d_in[3];
    const float* eb = (const float*)d_in[4];

    float* out    = (float*)d_out;
    float* logits = out + (size_t)T_TOK * DIM;

    char*   ws      = (char*)d_ws;
    u16*    xb      = (u16*)(ws + XB_OFF);
    u16*    wb      = (u16*)(ws + WB_OFF);
    int*    counts  = (int*)(ws + CNT_OFF);
    int*    lists   = (int*)(ws + LIST_OFF);
    float4* selw    = (float4*)(ws + SELW_OFF);
    u16*    contrib = (u16*)(ws + CONTRIB_OFF);

    hipMemsetAsync((void*)(ws + CNT_OFF), 0, 512, stream);
    k_router<<<T_TOK / RT_PB, 256, 0, stream>>>(x, gw, gb, logits, xb, counts,
                                                lists, selw, ew, wb);

    if (ws_size >= WS_NEED) {
        k_gemm<<<NEXP * 64 * 4, 512, 0, stream>>>(xb, wb, counts, lists, contrib);
        k_combine<<<T_TOK / 4, 256, 0, stream>>>(contrib, selw, eb, out);
    } else {
        k_bias<<<T_TOK / 4, 256, 0, stream>>>(selw, eb, out);
        k_gemm_atomic<<<NEXP * 128 * 8, 256, 0, stream>>>(xb, wb, counts, lists, selw, out);
    }
}

// Round 12
// 154.314 us; speedup vs baseline: 2.1430x; 1.1307x over previous
//
#include <hip/hip_runtime.h>
#include <hip/hip_bf16.h>

typedef unsigned short u16;
typedef unsigned int u32;

#define T_TOK 16384
#define DIM   1024
#define NEXP  8

// ---------- workspace layout (bytes) ----------
#define XB_OFF      0
#define WB_OFF      33554432
#define CNT_OFF     50331648
#define LIST_OFF    50332160
#define SELW_OFF    50856448
#define CONTRIB_OFF 51380736
#define WS_NEED     118489600ULL

__device__ __forceinline__ u16 f2bf(float f) {
    u32 u = __float_as_uint(f);
    u += 0x7fff + ((u >> 16) & 1);   // round-to-nearest-even
    return (u16)(u >> 16);
}
__device__ __forceinline__ float bf2f(u16 u) {
    return __uint_as_float(((u32)u) << 16);
}

// Router + fused expert-weight cvt (unchanged).
#define RT_PB 32

__global__ __launch_bounds__(256) void k_router(
    const float* __restrict__ x, const float* __restrict__ gw,
    const float* __restrict__ gb, float* __restrict__ logits,
    u16* __restrict__ xb, int* __restrict__ counts,
    int* __restrict__ lists, float4* __restrict__ selw,
    const float* __restrict__ ew, u16* __restrict__ wb)
{
    const int tid  = threadIdx.x;
    const int lane = tid & 63;
    const int w    = tid >> 6;

    __shared__ int   s_sel0[RT_PB], s_sel1[RT_PB];
    __shared__ int   s_lcnt[NEXP], s_gbase[NEXP];

    if (tid < NEXP) s_lcnt[tid] = 0;

    for (int i = 0; i < 8; ++i) {
        const int l = w * 8 + i;
        const int t = blockIdx.x * RT_PB + l;

        const float* xr = x + (size_t)t * DIM;
        float4 xs[4];
#pragma unroll
        for (int j = 0; j < 4; ++j)
            xs[j] = *reinterpret_cast<const float4*>(xr + (j * 64 + lane) * 4);

        float acc[NEXP];
#pragma unroll
        for (int e = 0; e < NEXP; ++e) {
            const float* gr = gw + e * DIM;
            float s = 0.f;
#pragma unroll
            for (int j = 0; j < 4; ++j) {
                float4 g = *reinterpret_cast<const float4*>(gr + (j * 64 + lane) * 4);
                s += xs[j].x * g.x + xs[j].y * g.y + xs[j].z * g.z + xs[j].w * g.w;
            }
            acc[e] = s;
        }
#pragma unroll
        for (int off = 1; off < 64; off <<= 1) {
#pragma unroll
            for (int e = 0; e < NEXP; ++e) acc[e] += __shfl_xor(acc[e], off);
        }
#pragma unroll
        for (int e = 0; e < NEXP; ++e) acc[e] += gb[e];

        int i0 = 0; float v0 = acc[0];
#pragma unroll
        for (int e = 1; e < NEXP; ++e) if (acc[e] > v0) { v0 = acc[e]; i0 = e; }
        int i1 = -1; float v1 = -3.4e38f;
#pragma unroll
        for (int e = 0; e < NEXP; ++e) if (e != i0 && acc[e] > v1) { v1 = acc[e]; i1 = e; }
        float e1  = __expf(v1 - v0);
        float inv = 1.f / (1.f + e1);
        float w0 = inv, w1 = e1 * inv;

        u16* xrow = xb + (size_t)t * DIM;
#pragma unroll
        for (int j = 0; j < 4; ++j) {
            int c = (j * 64 + lane) * 4;
            float4 v = xs[j];
            ushort4 u;
            u.x = f2bf(v.x); u.y = f2bf(v.y); u.z = f2bf(v.z); u.w = f2bf(v.w);
            *reinterpret_cast<ushort4*>(xrow + c) = u;
        }
        if (lane == 0) {
            float4 lo = make_float4(acc[0], acc[1], acc[2], acc[3]);
            float4 hi = make_float4(acc[4], acc[5], acc[6], acc[7]);
            *reinterpret_cast<float4*>(logits + (size_t)t * NEXP)     = lo;
            *reinterpret_cast<float4*>(logits + (size_t)t * NEXP + 4) = hi;
            selw[t] = make_float4(__int_as_float(i0), __int_as_float(i1), w0, w1);
            s_sel0[l] = i0; s_sel1[l] = i1;
        }
    }
    __syncthreads();

    int i0 = 0, i1 = 0, r0 = 0, r1 = 0;
    if (tid < RT_PB) {
        i0 = s_sel0[tid]; i1 = s_sel1[tid];
        r0 = atomicAdd(&s_lcnt[i0], 1);
        r1 = atomicAdd(&s_lcnt[i1], 1);
    }
    __syncthreads();
    if (tid < NEXP)
        s_gbase[tid] = atomicAdd(&counts[tid * 16], s_lcnt[tid]);
    __syncthreads();
    if (tid < RT_PB) {
        int t  = blockIdx.x * RT_PB + tid;
        lists[i0 * T_TOK + s_gbase[i0] + r0] = t * 2;
        lists[i1 * T_TOK + s_gbase[i1] + r1] = t * 2 + 1;
    }

    const int n4 = NEXP * DIM * DIM / 4;
    const int stride = gridDim.x * 256;
    for (int i = blockIdx.x * 256 + tid; i < n4; i += stride) {
        float4 v = reinterpret_cast<const float4*>(ew)[i];
        ushort4 u;
        u.x = f2bf(v.x); u.y = f2bf(v.y); u.z = f2bf(v.z); u.w = f2bf(v.w);
        reinterpret_cast<ushort4*>(wb)[i] = u;
    }
}

// ======================= grouped GEMM v7: register-fragment double-buffer.
// 128x128 tile, 4 waves (2x2), wave-tile 64x64. 64 KiB LDS dbuf -> 2
// blocks/CU. Per K-tile iteration u (all waits prove ITERATION-OLD ops):
//   LGKM0+sched_barrier  : reads issued at u-1 done (frees buf[u&1] WAR,
//                          and proves MFMA(u) operands -- no wait later)
//   VMW0                 : gloads issued at u-1 (tile u+1) done
//   BAR                  : makes both proofs collective
//   STAGE(buf[u&1], u+2) : 8 gloads, overwrite freed buffer
//   LDSET(set[u^1], buf[(u+1)&1]) : 16 ds_reads for NEXT tile, nonblocking
//   PRIO1; 32 MFMA from set[u&1] (zero internal waits); PRIO0
// MFMA burst never waits on freshly-issued reads -- the r5-r11 invariant
// (~900cy/phase latency exposure, MfmaUtil pinned ~27%) is removed.
// Swizzle: 16B-chunk slot=(chunk+row)&7 both-sides (16-row strides preserve
// &7 -> 2 read-base regs + imm offsets). Expert->XCD pinned grid.

typedef __attribute__((ext_vector_type(8))) short bf16x8;
typedef __attribute__((ext_vector_type(4))) float f32x4;

#define GLDS16(g, l) __builtin_amdgcn_global_load_lds( \
    (const __attribute__((address_space(1))) void*)(g), \
    (__attribute__((address_space(3))) void*)(l), 16, 0, 0)

#define BAR() __builtin_amdgcn_s_barrier()
#define PRIO1() __builtin_amdgcn_s_setprio(1)
#define PRIO0() __builtin_amdgcn_s_setprio(0)
#define VMW0() asm volatile("s_waitcnt vmcnt(0)" ::: "memory")
#define LGKM0() do { asm volatile("s_waitcnt lgkmcnt(0)" ::: "memory"); \
                     __builtin_amdgcn_sched_barrier(0); } while (0)

__global__ __launch_bounds__(256, 2) void k_gemm(
    const u16* __restrict__ xb, const u16* __restrict__ wb,
    const int* __restrict__ counts, const int* __restrict__ lists,
    u16* __restrict__ contrib)
{
    __shared__ char lds[65536];   // buf b*32768 | A [0,16384) | B [16384,32768)

    // expert->XCD pinning: XCD x owns expert x's 1024 slots (128 mt x 8 nt)
    const int bid = (blockIdx.x & 7) * 1024 + (blockIdx.x >> 3);
    const int e   = bid >> 10;
    const int mt  = (bid >> 3) & 127;
    const int nt  = bid & 7;
    const int cnt = counts[e * 16];
    if (mt * 128 >= cnt) return;

    const int tid  = threadIdx.x;
    const int lane = tid & 63;
    const int wid  = tid >> 6;
    const int wm   = wid >> 1;   // 0..1
    const int wn   = wid & 1;    // 0..1
    const int listbase = e * T_TOK;

    // ---- staging maps: wave w instr i covers rows w*32+i*8+(lane>>3),
    // dest slot lane&7 (linear lane*16B); source chunk = ((lane&7)-row)&7.
    const int l8  = lane >> 3;
    const int cgs = ((lane & 7) - l8) & 7;
    const char* xbB = (const char*)xb;
    const char* wbB = (const char*)wb;
    u32 aoff[4], boff[4];
#pragma unroll
    for (int i = 0; i < 4; ++i) {
        int r    = wid * 32 + i * 8 + l8;
        int slot = mt * 128 + r;
        int tok  = lists[listbase + (slot < cnt ? slot : cnt - 1)] >> 1;
        aoff[i]  = (u32)tok * 2048 + (u32)cgs * 16;
        boff[i]  = ((u32)e << 21) + (u32)(nt * 128 + r) * 2048 + (u32)cgs * 16;
    }

#define STAGE(b, t) do { \
    _Pragma("unroll") for (int i = 0; i < 4; ++i) \
        GLDS16(xbB + aoff[i] + (t) * 128, lds + (b) * 32768 + (wid * 4 + i) * 1024); \
    _Pragma("unroll") for (int i = 0; i < 4; ++i) \
        GLDS16(wbB + boff[i] + (t) * 128, lds + (b) * 32768 + 16384 + (wid * 4 + i) * 1024); \
} while (0)

    // ---- read bases: row=(wm|wn)*64+mi*16+l15, chunk=kk*4+c0,
    // slot=(chunk+l15)&7 (row mod 8 == l15 mod 8). addr=row*128+slot*16.
    const int l15 = lane & 15;
    const int c0  = lane >> 4;
    const u32 ra0 = (u32)(wm * 64 + l15) * 128 + (u32)(((c0 + l15) & 7) * 16);
    const u32 ra1 = (u32)(wm * 64 + l15) * 128 + (u32)(((4 + c0 + l15) & 7) * 16);
    const u32 rb0 = 16384u + (u32)(wn * 64 + l15) * 128 + (u32)(((c0 + l15) & 7) * 16);
    const u32 rb1 = 16384u + (u32)(wn * 64 + l15) * 128 + (u32)(((4 + c0 + l15) & 7) * 16);

    bf16x8 A0[8], B0[8], A1[8], B1[8];
#define LDSET(Ad, Bd, b) do { \
    _Pragma("unroll") for (int mi = 0; mi < 4; ++mi) { \
        Ad[mi * 2 + 0] = *(const bf16x8*)(lds + (b) * 32768 + ra0 + mi * 2048); \
        Ad[mi * 2 + 1] = *(const bf16x8*)(lds + (b) * 32768 + ra1 + mi * 2048); \
    } \
    _Pragma("unroll") for (int ni = 0; ni < 4; ++ni) { \
        Bd[ni * 2 + 0] = *(const bf16x8*)(lds + (b) * 32768 + rb0 + ni * 2048); \
        Bd[ni * 2 + 1] = *(const bf16x8*)(lds + (b) * 32768 + rb1 + ni * 2048); \
    } \
} while (0)

    f32x4 acc[4][4];
#pragma unroll
    for (int mi = 0; mi < 4; ++mi)
#pragma unroll
        for (int ni = 0; ni < 4; ++ni) acc[mi][ni] = (f32x4)0.f;

#define MFMAS(As, Bs) do { \
    _Pragma("unroll") for (int kk = 0; kk < 2; ++kk) \
    _Pragma("unroll") for (int mi = 0; mi < 4; ++mi) \
    _Pragma("unroll") for (int ni = 0; ni < 4; ++ni) \
        acc[mi][ni] = __builtin_amdgcn_mfma_f32_16x16x32_bf16( \
            As[mi * 2 + kk], Bs[ni * 2 + kk], acc[mi][ni], 0, 0, 0); \
} while (0)

#define ITER(U, Ac, Bc, An, Bn) do { \
    LGKM0(); \
    if ((U) >= 1) VMW0(); \
    BAR(); \
    if ((U) <= 13) STAGE((U) & 1, (U) + 2); \
    if ((U) <= 14) LDSET(An, Bn, ((U) + 1) & 1); \
    PRIO1(); MFMAS(Ac, Bc); PRIO0(); \
} while (0)

    // prologue: stage tiles 0,1; preload frags(0)
    STAGE(0, 0); STAGE(1, 1);
    VMW0(); BAR();
    LDSET(A0, B0, 0);

#pragma unroll
    for (int h = 0; h < 8; ++h) {
        ITER(2 * h,     A0, B0, A1, B1);
        ITER(2 * h + 1, A1, B1, A0, B0);
    }

    // epilogue: C/D layout col=lane&15, row=(lane>>4)*4+reg
    const int rbase = c0 * 4;
    const int cbase = nt * 128 + wn * 64 + l15;
#pragma unroll
    for (int mi = 0; mi < 4; ++mi) {
#pragma unroll
        for (int r = 0; r < 4; ++r) {
            int slot = mt * 128 + wm * 64 + mi * 16 + rbase + r;
            if (slot < cnt) {
                int lv = lists[listbase + slot];
                u16* crow = contrib + (size_t)lv * DIM + cbase;
#pragma unroll
                for (int ni = 0; ni < 4; ++ni)
                    crow[ni * 16] = f2bf(acc[mi][ni][r]);
            }
        }
    }
}

// out[t] = w0*(c0 + b[e0]) + w1*(c1 + b[e1]); 4 tokens/block
__global__ __launch_bounds__(256) void k_combine(
    const u16* __restrict__ contrib, const float4* __restrict__ selw,
    const float* __restrict__ eb, float* __restrict__ out)
{
    const int lane = threadIdx.x & 63;
    const int t    = blockIdx.x * 4 + (threadIdx.x >> 6);
    float4 sw = selw[t];
    const int e0 = __float_as_int(sw.x);
    const int e1 = __float_as_int(sw.y);
    const float w0 = sw.z, w1 = sw.w;
    const u16* c0 = contrib + (size_t)(t * 2) * DIM;
    const u16* c1 = c0 + DIM;
    const float* b0 = eb + e0 * DIM;
    const float* b1 = eb + e1 * DIM;
    float* orow = out + (size_t)t * DIM;
#pragma unroll
    for (int j = 0; j < 2; ++j) {
        const int c = (j * 64 + lane) * 8;
        uint4 u0 = *reinterpret_cast<const uint4*>(c0 + c);
        uint4 u1 = *reinterpret_cast<const uint4*>(c1 + c);
        const u16* p0 = (const u16*)&u0;
        const u16* p1 = (const u16*)&u1;
#pragma unroll
        for (int h = 0; h < 2; ++h) {
            float4 bb0 = *reinterpret_cast<const float4*>(b0 + c + h * 4);
            float4 bb1 = *reinterpret_cast<const float4*>(b1 + c + h * 4);
            float4 o;
            o.x = w0 * (bf2f(p0[h*4+0]) + bb0.x) + w1 * (bf2f(p1[h*4+0]) + bb1.x);
            o.y = w0 * (bf2f(p0[h*4+1]) + bb0.y) + w1 * (bf2f(p1[h*4+1]) + bb1.y);
            o.z = w0 * (bf2f(p0[h*4+2]) + bb0.z) + w1 * (bf2f(p1[h*4+2]) + bb1.z);
            o.w = w0 * (bf2f(p0[h*4+3]) + bb0.w) + w1 * (bf2f(p1[h*4+3]) + bb1.w);
            *reinterpret_cast<float4*>(orow + c + h * 4) = o;
        }
    }
}

// fallback: bias-init + atomic GEMM when ws too small for contrib
__global__ __launch_bounds__(256) void k_bias(
    const float4* __restrict__ selw, const float* __restrict__ eb,
    float* __restrict__ out)
{
    const int lane = threadIdx.x & 63;
    const int t    = blockIdx.x * 4 + (threadIdx.x >> 6);
    float4 sw = selw[t];
    const float* b0 = eb + __float_as_int(sw.x) * DIM;
    const float* b1 = eb + __float_as_int(sw.y) * DIM;
    float* orow = out + (size_t)t * DIM;
#pragma unroll
    for (int j = 0; j < 4; ++j) {
        int c = (j * 64 + lane) * 4;
        float4 f0 = *reinterpret_cast<const float4*>(b0 + c);
        float4 f1 = *reinterpret_cast<const float4*>(b1 + c);
        float4 o;
        o.x = sw.z * f0.x + sw.w * f1.x;
        o.y = sw.z * f0.y + sw.w * f1.y;
        o.z = sw.z * f0.z + sw.w * f1.z;
        o.w = sw.z * f0.w + sw.w * f1.w;
        *reinterpret_cast<float4*>(orow + c) = o;
    }
}

__global__ __launch_bounds__(256) void k_gemm_atomic(
    const u16* __restrict__ xb, const u16* __restrict__ wb,
    const int* __restrict__ counts, const int* __restrict__ lists,
    const float4* __restrict__ selw, float* __restrict__ out)
{
    __shared__ u16 ldsA[128 * 64];
    __shared__ u16 ldsB[128 * 64];
    const int bid = blockIdx.x;
    const int e   = bid >> 10;
    const int mt  = (bid >> 3) & 127;
    const int nt  = bid & 7;
    const int cnt = counts[e * 16];
    if (mt * 128 >= cnt) return;
    const int tid  = threadIdx.x;
    const int lane = tid & 63;
    const int wid  = tid >> 6;
    const int wr   = wid >> 1, wc = wid & 1;
    const int srow = tid >> 3;
    const int skc  = (tid & 7) * 8;
    const int listbase = e * T_TOK;
    int tokA[4];
#pragma unroll
    for (int i = 0; i < 4; ++i) {
        int slot = mt * 128 + i * 32 + srow;
        tokA[i] = lists[listbase + (slot < cnt ? slot : cnt - 1)] >> 1;
    }
    const size_t wbase = ((size_t)e << 20) + (size_t)(nt * 128) * DIM;
    f32x4 acc[4][4];
#pragma unroll
    for (int mi = 0; mi < 4; ++mi)
#pragma unroll
        for (int ni = 0; ni < 4; ++ni) acc[mi][ni] = (f32x4)0.f;
    for (int k0 = 0; k0 < DIM; k0 += 64) {
        uint4 ra[4], rb[4];
#pragma unroll
        for (int i = 0; i < 4; ++i) {
            ra[i] = *reinterpret_cast<const uint4*>(xb + (size_t)tokA[i] * DIM + k0 + skc);
            rb[i] = *reinterpret_cast<const uint4*>(wb + wbase + (size_t)(i * 32 + srow) * DIM + k0 + skc);
        }
        __syncthreads();
#pragma unroll
        for (int i = 0; i < 4; ++i) {
            *reinterpret_cast<uint4*>(ldsA + (i * 32 + srow) * 64 + skc) = ra[i];
            *reinterpret_cast<uint4*>(ldsB + (i * 32 + srow) * 64 + skc) = rb[i];
        }
        __syncthreads();
#pragma unroll
        for (int ks = 0; ks < 2; ++ks) {
            const int kof = ks * 32 + (lane >> 4) * 8;
            bf16x8 af[4], bfr[4];
#pragma unroll
            for (int mi = 0; mi < 4; ++mi)
                af[mi] = *reinterpret_cast<const bf16x8*>(ldsA + (wr * 64 + mi * 16 + (lane & 15)) * 64 + kof);
#pragma unroll
            for (int ni = 0; ni < 4; ++ni)
                bfr[ni] = *reinterpret_cast<const bf16x8*>(ldsB + (wc * 64 + ni * 16 + (lane & 15)) * 64 + kof);
#pragma unroll
            for (int mi = 0; mi < 4; ++mi)
#pragma unroll
                for (int ni = 0; ni < 4; ++ni)
                    acc[mi][ni] = __builtin_amdgcn_mfma_f32_16x16x32_bf16(af[mi], bfr[ni], acc[mi][ni], 0, 0, 0);
        }
        __syncthreads();
    }
    const int rbase = (lane >> 4) * 4;
    const int cbase = nt * 128 + wc * 64 + (lane & 15);
#pragma unroll
    for (int mi = 0; mi < 4; ++mi) {
#pragma unroll
        for (int r = 0; r < 4; ++r) {
            int slot = mt * 128 + wr * 64 + mi * 16 + rbase + r;
            if (slot < cnt) {
                int lv = lists[listbase + slot];
                int tok = lv >> 1;
                float4 sw = selw[tok];
                float wgt = (lv & 1) ? sw.w : sw.z;
                float* orow = out + (size_t)tok * DIM + cbase;
#pragma unroll
                for (int ni = 0; ni < 4; ++ni)
                    atomicAdd(orow + ni * 16, acc[mi][ni][r] * wgt);
            }
        }
    }
}

extern "C" void kernel_launch(void* const* d_in, const int* in_sizes, int n_in,
                              void* d_out, int out_size, void* d_ws, size_t ws_size,
                              hipStream_t stream) {
    const float* x  = (const float*)d_in[0];
    const float* gw = (const float*)d_in[1];
    const float* gb = (const float*)d_in[2];
    const float* ew = (const float*)d_in[3];
    const float* eb = (const float*)d_in[4];

    float* out    = (float*)d_out;
    float* logits = out + (size_t)T_TOK * DIM;

    char*   ws      = (char*)d_ws;
    u16*    xb      = (u16*)(ws + XB_OFF);
    u16*    wb      = (u16*)(ws + WB_OFF);
    int*    counts  = (int*)(ws + CNT_OFF);
    int*    lists   = (int*)(ws + LIST_OFF);
    float4* selw    = (float4*)(ws + SELW_OFF);
    u16*    contrib = (u16*)(ws + CONTRIB_OFF);

    hipMemsetAsync((void*)(ws + CNT_OFF), 0, 512, stream);
    k_router<<<T_TOK / RT_PB, 256, 0, stream>>>(x, gw, gb, logits, xb, counts,
                                                lists, selw, ew, wb);

    if (ws_size >= WS_NEED) {
        k_gemm<<<NEXP * 128 * 8, 256, 0, stream>>>(xb, wb, counts, lists, contrib);
        k_combine<<<T_TOK / 4, 256, 0, stream>>>(contrib, selw, eb, out);
    } else {
        k_bias<<<T_TOK / 4, 256, 0, stream>>>(selw, eb, out);
        k_gemm_atomic<<<NEXP * 128 * 8, 256, 0, stream>>>(xb, wb, counts, lists, selw, out);
    }
}